// Round 4
// baseline (440.290 us; speedup 1.0000x reference)
//
#include <hip/hip_runtime.h>
#include <cstdint>

typedef unsigned short u16t;
typedef float v4f __attribute__((ext_vector_type(4)));
typedef short v8s __attribute__((ext_vector_type(8)));

#define HIDDEN 2048
#define NHEAD 16
#define HDIM 128
#define SEQ 2048
#define BATCH 2
#define MROWS (BATCH * SEQ) /* 4096 */

__device__ __forceinline__ float bf2f(u16t u) {
  return __builtin_bit_cast(float, (uint32_t)((uint32_t)u << 16));
}
__device__ __forceinline__ u16t f2bf(float f) {
  uint32_t u = __builtin_bit_cast(uint32_t, f);
  u += 0x7FFFu + ((u >> 16) & 1u);
  return (u16t)(u >> 16);
}
__device__ __forceinline__ ushort4 f2bf4(float4 v) {
  ushort4 r;
  r.x = f2bf(v.x); r.y = f2bf(v.y); r.z = f2bf(v.z); r.w = f2bf(v.w);
  return r;
}

// async global->LDS, 16B per lane. LDS dest must be wave-uniform base + lane*16.
__device__ __forceinline__ void gld_lds16(const u16t* g, u16t* l) {
  __builtin_amdgcn_global_load_lds(
      (const __attribute__((address_space(1))) uint32_t*)g,
      (__attribute__((address_space(3))) uint32_t*)l, 16, 0, 0);
}

// ---------------------------------------------------------------------------
// fp32 -> bf16 elementwise convert (8 elems/thread)
// ---------------------------------------------------------------------------
__global__ __launch_bounds__(256) void cvt_bf16(const float* __restrict__ src,
                                                u16t* __restrict__ dst, int n8) {
  int i = blockIdx.x * 256 + threadIdx.x;
  if (i < n8) {
    float4 a = ((const float4*)src)[2 * i];
    float4 b = ((const float4*)src)[2 * i + 1];
    union { ushort4 h[2]; uint4 u; } pk;
    pk.h[0] = f2bf4(a);
    pk.h[1] = f2bf4(b);
    ((uint4*)dst)[i] = pk.u;
  }
}

// All four weight matrices in one launch (each HIDDEN*HIDDEN, n8 = 2^19 each).
__global__ __launch_bounds__(256) void cvt_bf16_w4(
    const float* __restrict__ s0, const float* __restrict__ s1,
    const float* __restrict__ s2, const float* __restrict__ s3,
    u16t* __restrict__ d0, u16t* __restrict__ d1,
    u16t* __restrict__ d2, u16t* __restrict__ d3) {
  int i = blockIdx.x * 256 + threadIdx.x;
  int sel = i >> 19;          // WN8 == 2^19
  int j = i & 0x7FFFF;
  const float* src = (sel == 0) ? s0 : (sel == 1) ? s1 : (sel == 2) ? s2 : s3;
  u16t* dst = (sel == 0) ? d0 : (sel == 1) ? d1 : (sel == 2) ? d2 : d3;
  float4 a = ((const float4*)src)[2 * j];
  float4 b = ((const float4*)src)[2 * j + 1];
  union { ushort4 h[2]; uint4 u; } pk;
  pk.h[0] = f2bf4(a);
  pk.h[1] = f2bf4(b);
  ((uint4*)dst)[j] = pk.u;
}

// ---------------------------------------------------------------------------
// Pipelined GEMM, 256x256 tile: C[m,n] = sum_k A[m,k]*B[n,k], bf16 in, fp32 acc.
// BK=32, 512 thr = 8 waves (2M x 4N), per-wave 128x64 (MFMA:ds_read = 2.67).
// 3 LDS bufs x (A 16KB + B 16KB) = 96 KB; tile kt uses buf kt%3, prefetch
// depth 2, counted vmcnt(4) at end-of-tile (R3-verified rotation proof, new
// constants). XOR swizzle chunk16 ^= (row>>1)&3 (pre-swizzled global source,
// linear gld_lds dest, swizzled ds_read; 2-way max on reads). T5 setprio.
// XCD-chunked bijective grid swizzle: each XCD owns 2 m-rows of the grid so
// its 2 A-panels (2 MB) stay L2-resident -> fetch ~210MB vs 768MB.
// MODE 0: fused QKV (B = [Wq;Wk;Wv], 24x16 grid): n<2048 -> q bf16,
//         n<4096 -> k bf16, else vt[n-4096][m] bf16 (transposed, for flash).
// MODE 1: attn-out (B = Wo, 8x16 grid): f32 C[m][n].
// ---------------------------------------------------------------------------
template <int MODE>
__global__ __launch_bounds__(512) void gemm_fused(const u16t* __restrict__ A,
                                                  const u16t* __restrict__ B,
                                                  u16t* __restrict__ qo,
                                                  u16t* __restrict__ ko,
                                                  u16t* __restrict__ vto,
                                                  float* __restrict__ fo) {
  __shared__ u16t lds[49152];  // A bufs [0,24576), B bufs [24576,49152)

  const int NX = (MODE == 0) ? 24 : 8;    // grid x tiles
  const int CPX = (MODE == 0) ? 48 : 16;  // WGs per XCD chunk (nwg/8)
  const int id = blockIdx.x;
  const int swz = (id & 7) * CPX + (id >> 3);
  const int tx = swz % NX;
  const int ty = swz / NX;
  const int n0 = tx * 256;
  const int m0 = ty * 256;

  const int t = threadIdx.x;
  const int lane = t & 63;
  const int w = t >> 6;        // 0..7
  const int wm = w >> 2;       // 0..1  (M half: 128 rows)
  const int wn = w & 3;        // 0..3  (N quarter: 64 cols)
  const int l15 = lane & 15;
  const int quad = lane >> 4;

  // staging: thread t covers 16B: row = t>>2 (of 128-row half), phys chunk t&3.
  // global source fetches logical chunk (t&3) ^ ((t>>3)&3)  [inverse swizzle].
  const int srow = t >> 2;
  const int sc8 = ((t & 3) ^ ((t >> 3) & 3)) * 8;
  const u16t* Ag = A + (size_t)(m0 + srow) * HIDDEN + sc8;
  const u16t* Bg = B + (size_t)(n0 + srow) * HIDDEN + sc8;

  // ds_read: logical chunk = quad, physical = quad ^ ((row>>1)&3); row bases
  // are multiples of 16 so only l15 contributes.
  const int pcol = (quad ^ ((l15 >> 1) & 3)) * 8;

  v4f acc[8][4];
#pragma unroll
  for (int i = 0; i < 8; ++i)
#pragma unroll
    for (int j = 0; j < 4; ++j) acc[i][j] = (v4f){0.f, 0.f, 0.f, 0.f};

  const int KT = HIDDEN / 32;  // 64 K-tiles

  // prologue: stage tiles 0,1 into bufs 0,1 (4 loads each; tile 0 oldest)
#pragma unroll
  for (int tt = 0; tt < 2; ++tt) {
    const int kb = tt * 32;
    gld_lds16(Ag + kb, &lds[tt * 8192 + t * 8]);
    gld_lds16(Ag + kb + 128 * HIDDEN, &lds[tt * 8192 + 4096 + t * 8]);
    gld_lds16(Bg + kb, &lds[24576 + tt * 8192 + t * 8]);
    gld_lds16(Bg + kb + 128 * HIDDEN, &lds[24576 + tt * 8192 + 4096 + t * 8]);
  }
  asm volatile("s_waitcnt vmcnt(4)" ::: "memory");  // tile 0 landed
  __builtin_amdgcn_s_barrier();

  int b = 0;  // tile kt uses buf kt%3
  for (int kt = 0; kt < KT; ++kt) {
    const int kb2 = kt * 32 + 64;         // K offset of tile kt+2
    const int b2 = (b >= 1) ? b - 1 : 2;  // (kt+2)%3 — was tile kt-1's buf
    const u16t* Asb = &lds[b * 8192];
    const u16t* Bsb = &lds[24576 + b * 8192];
    const bool pre = (kt + 2 < KT);

    // ---------------- phase 1: m-tiles 0..3 ----------------
    v8s bfr[4];
#pragma unroll
    for (int j = 0; j < 4; ++j)
      bfr[j] = *(const v8s*)&Bsb[(wn * 64 + j * 16 + l15) * 32 + pcol];
    v8s af[4];
#pragma unroll
    for (int i = 0; i < 4; ++i)
      af[i] = *(const v8s*)&Asb[(wm * 128 + i * 16 + l15) * 32 + pcol];
    if (pre) {
      gld_lds16(Ag + kb2, &lds[b2 * 8192 + t * 8]);
      gld_lds16(Bg + kb2, &lds[24576 + b2 * 8192 + t * 8]);
    }
    __builtin_amdgcn_s_barrier();
    asm volatile("s_waitcnt lgkmcnt(0)" ::: "memory");
    __builtin_amdgcn_s_setprio(1);
#pragma unroll
    for (int i = 0; i < 4; ++i)
#pragma unroll
      for (int j = 0; j < 4; ++j)
        acc[i][j] = __builtin_amdgcn_mfma_f32_16x16x32_bf16(af[i], bfr[j], acc[i][j], 0, 0, 0);
    __builtin_amdgcn_s_setprio(0);
    __builtin_amdgcn_s_barrier();

    // ---------------- phase 2: m-tiles 4..7 ----------------
#pragma unroll
    for (int i = 0; i < 4; ++i)
      af[i] = *(const v8s*)&Asb[(wm * 128 + 64 + i * 16 + l15) * 32 + pcol];
    if (pre) {
      gld_lds16(Ag + kb2 + 128 * HIDDEN, &lds[b2 * 8192 + 4096 + t * 8]);
      gld_lds16(Bg + kb2 + 128 * HIDDEN, &lds[24576 + b2 * 8192 + 4096 + t * 8]);
    }
    __builtin_amdgcn_s_barrier();
    asm volatile("s_waitcnt lgkmcnt(0)" ::: "memory");
    __builtin_amdgcn_s_setprio(1);
#pragma unroll
    for (int i = 0; i < 4; ++i)
#pragma unroll
      for (int j = 0; j < 4; ++j)
        acc[4 + i][j] = __builtin_amdgcn_mfma_f32_16x16x32_bf16(af[i], bfr[j], acc[4 + i][j], 0, 0, 0);
    __builtin_amdgcn_s_setprio(0);
    // end of K-tile: tile kt+1 must have landed; keep tile kt+2's 4 in flight
    if (pre) {
      asm volatile("s_waitcnt vmcnt(4)" ::: "memory");
    } else if (kt + 1 < KT) {
      asm volatile("s_waitcnt vmcnt(0)" ::: "memory");
    }
    __builtin_amdgcn_s_barrier();
    b = (b == 2) ? 0 : b + 1;
  }

  // ---------------- epilogue ----------------
  if (MODE == 1) {
#pragma unroll
    for (int i = 0; i < 8; ++i) {
#pragma unroll
      for (int j = 0; j < 4; ++j) {
        int col = n0 + wn * 64 + j * 16 + l15;
#pragma unroll
        for (int r = 0; r < 4; ++r) {
          int row = m0 + wm * 128 + i * 16 + quad * 4 + r;
          fo[(size_t)row * HIDDEN + col] = acc[i][j][r];
        }
      }
    }
  } else if (tx < 16) {
    // q or k range: bf16 [m][2048]
    u16t* dst = (tx < 8) ? qo : ko;
    const int cb = n0 & 2047;
#pragma unroll
    for (int i = 0; i < 8; ++i) {
#pragma unroll
      for (int j = 0; j < 4; ++j) {
        int col = cb + wn * 64 + j * 16 + l15;
#pragma unroll
        for (int r = 0; r < 4; ++r) {
          int row = m0 + wm * 128 + i * 16 + quad * 4 + r;
          dst[(size_t)row * HIDDEN + col] = f2bf(acc[i][j][r]);
        }
      }
    }
  } else {
    // V range: transposed bf16 vt[n-4096][m], two 128-n half passes via LDS
    const int nv0 = n0 - 4096;
    u16t* Ct = (u16t*)lds;  // [128][264] u16 = 67.5 KB
#pragma unroll
    for (int h = 0; h < 2; ++h) {
      __syncthreads();
      if ((wn >> 1) == h) {
#pragma unroll
        for (int i = 0; i < 8; ++i)
#pragma unroll
          for (int j = 0; j < 4; ++j)
#pragma unroll
            for (int r = 0; r < 4; ++r)
              Ct[((wn & 1) * 64 + j * 16 + l15) * 264 +
                 wm * 128 + i * 16 + quad * 4 + r] = f2bf(acc[i][j][r]);
      }
      __syncthreads();
#pragma unroll
      for (int it = 0; it < 8; ++it) {
        int idx = t + it * 512;   // 0..4095
        int nl = idx >> 5;        // 0..127
        int mc = idx & 31;        // 0..31 (16B chunks over 256 m)
        *(uint4*)&vto[(size_t)(nv0 + h * 128 + nl) * MROWS + m0 + mc * 8] =
            *(const uint4*)&Ct[nl * 264 + mc * 8];
      }
    }
  }
}

// ---------------------------------------------------------------------------
// Fallback GEMM (m97 structure) for small-workspace path: B is fp32.
// ---------------------------------------------------------------------------
template <int OUT_F32>
__global__ __launch_bounds__(256) void gemm_a16(const u16t* __restrict__ A,
                                                const void* __restrict__ Bp,
                                                void* __restrict__ Cp) {
  __shared__ u16t As[128 * 32];
  __shared__ u16t Bs[128 * 32];

  const int n0 = blockIdx.x * 128;
  const int m0 = blockIdx.y * 128;
  const int t = threadIdx.x;
  const int lane = t & 63;
  const int w = t >> 6;
  const int wm = w & 1;
  const int wn = w >> 1;
  const int l15 = lane & 15;
  const int quad = lane >> 4;

  v4f acc[4][4];
#pragma unroll
  for (int i = 0; i < 4; ++i)
#pragma unroll
    for (int j = 0; j < 4; ++j) acc[i][j] = (v4f){0.f, 0.f, 0.f, 0.f};

  for (int kb = 0; kb < HIDDEN; kb += 32) {
#pragma unroll
    for (int j = 0; j < 2; ++j) {
      int idx = t + j * 256;
      int row = idx >> 2;
      int ch = (idx & 3) * 8;
      gld_lds16(&A[(size_t)(m0 + row) * HIDDEN + kb + ch], &As[idx * 8]);
    }
    {
      const float* B = (const float*)Bp;
#pragma unroll
      for (int j = 0; j < 4; ++j) {
        int idx = t + j * 256;
        int row = idx >> 3;
        int c4 = (idx & 7) * 4;
        float4 bv = *(const float4*)&B[(size_t)(n0 + row) * HIDDEN + kb + c4];
        *(ushort4*)&Bs[row * 32 + c4] = f2bf4(bv);
      }
    }
    __syncthreads();

    v8s af[4], bf[4];
#pragma unroll
    for (int mt = 0; mt < 4; ++mt)
      af[mt] = *(const v8s*)&As[(wm * 64 + mt * 16 + l15) * 32 + quad * 8];
#pragma unroll
    for (int nt = 0; nt < 4; ++nt)
      bf[nt] = *(const v8s*)&Bs[(wn * 64 + nt * 16 + l15) * 32 + quad * 8];

#pragma unroll
    for (int mt = 0; mt < 4; ++mt)
#pragma unroll
      for (int nt = 0; nt < 4; ++nt)
        acc[mt][nt] = __builtin_amdgcn_mfma_f32_16x16x32_bf16(af[mt], bf[nt], acc[mt][nt], 0, 0, 0);
    __syncthreads();
  }

#pragma unroll
  for (int mt = 0; mt < 4; ++mt) {
#pragma unroll
    for (int nt = 0; nt < 4; ++nt) {
      int col = n0 + wn * 64 + nt * 16 + l15;
#pragma unroll
      for (int r = 0; r < 4; ++r) {
        int row = m0 + wm * 64 + mt * 16 + quad * 4 + r;
        if (OUT_F32)
          ((float*)Cp)[(size_t)row * HIDDEN + col] = acc[mt][nt][r];
        else
          ((u16t*)Cp)[(size_t)row * HIDDEN + col] = f2bf(acc[mt][nt][r]);
      }
    }
  }
}

// Fallback V-projection with transposed output (fp32 B).
__global__ __launch_bounds__(256) void gemm_vt_f32(const u16t* __restrict__ A,
                                                   const void* __restrict__ Bp,
                                                   u16t* __restrict__ VtOut) {
  __shared__ u16t As[128 * 32];
  __shared__ u16t Bs[128 * 32];
  __shared__ u16t Ct[128 * 136];

  const int n0 = blockIdx.x * 128;
  const int m0 = blockIdx.y * 128;
  const int t = threadIdx.x;
  const int lane = t & 63;
  const int w = t >> 6;
  const int wm = w & 1;
  const int wn = w >> 1;
  const int l15 = lane & 15;
  const int quad = lane >> 4;

  v4f acc[4][4];
#pragma unroll
  for (int i = 0; i < 4; ++i)
#pragma unroll
    for (int j = 0; j < 4; ++j) acc[i][j] = (v4f){0.f, 0.f, 0.f, 0.f};

  for (int kb = 0; kb < HIDDEN; kb += 32) {
#pragma unroll
    for (int j = 0; j < 2; ++j) {
      int idx = t + j * 256;
      int row = idx >> 2;
      int ch = (idx & 3) * 8;
      gld_lds16(&A[(size_t)(m0 + row) * HIDDEN + kb + ch], &As[idx * 8]);
    }
    {
      const float* B = (const float*)Bp;
#pragma unroll
      for (int j = 0; j < 4; ++j) {
        int idx = t + j * 256;
        int row = idx >> 3;
        int c4 = (idx & 7) * 4;
        float4 bv = *(const float4*)&B[(size_t)(n0 + row) * HIDDEN + kb + c4];
        *(ushort4*)&Bs[row * 32 + c4] = f2bf4(bv);
      }
    }
    __syncthreads();

    v8s af[4], bf[4];
#pragma unroll
    for (int mt = 0; mt < 4; ++mt)
      af[mt] = *(const v8s*)&As[(wm * 64 + mt * 16 + l15) * 32 + quad * 8];
#pragma unroll
    for (int nt = 0; nt < 4; ++nt)
      bf[nt] = *(const v8s*)&Bs[(wn * 64 + nt * 16 + l15) * 32 + quad * 8];

#pragma unroll
    for (int mt = 0; mt < 4; ++mt)
#pragma unroll
      for (int nt = 0; nt < 4; ++nt)
        acc[mt][nt] = __builtin_amdgcn_mfma_f32_16x16x32_bf16(af[mt], bf[nt], acc[mt][nt], 0, 0, 0);
    __syncthreads();
  }

#pragma unroll
  for (int mt = 0; mt < 4; ++mt)
#pragma unroll
    for (int nt = 0; nt < 4; ++nt)
#pragma unroll
      for (int r = 0; r < 4; ++r)
        Ct[(wn * 64 + nt * 16 + l15) * 136 + (wm * 64 + mt * 16 + quad * 4 + r)] =
            f2bf(acc[mt][nt][r]);
  __syncthreads();

#pragma unroll
  for (int j = 0; j < 8; ++j) {
    int idx = t + j * 256;
    int nl = idx >> 4;
    int mc = idx & 15;
    *(uint4*)&VtOut[(size_t)(n0 + nl) * MROWS + m0 + mc * 8] =
        *(const uint4*)&Ct[nl * 136 + mc * 8];
  }
}

// ---------------------------------------------------------------------------
// RoPE in-place on q and k (bf16, [m][h*128+d])   (unchanged)
// ---------------------------------------------------------------------------
__global__ __launch_bounds__(256) void rope_k(u16t* __restrict__ q, u16t* __restrict__ k) {
  int idx = blockIdx.x * 256 + threadIdx.x;
  int i = idx & 63;
  int h = (idx >> 6) & (NHEAD - 1);
  int m = idx >> 10;
  int s = m & (SEQ - 1);
  float inv = __expf(-(float)i * 0.14391156831212787f);
  float th = (float)s * inv;
  float sn, cs;
  __sincosf(th, &sn, &cs);
  size_t base = (size_t)m * HIDDEN + h * HDIM + i;
  {
    float a = bf2f(q[base]), b = bf2f(q[base + 64]);
    q[base] = f2bf(a * cs - b * sn);
    q[base + 64] = f2bf(b * cs + a * sn);
  }
  {
    float a = bf2f(k[base]), b = bf2f(k[base + 64]);
    k[base] = f2bf(a * cs - b * sn);
    k[base + 64] = f2bf(b * cs + a * sn);
  }
}

// ---------------------------------------------------------------------------
// Flash attention v3 (byte-identical to the R1/R3 version that passed).
// ---------------------------------------------------------------------------
__global__ __launch_bounds__(512) void flash2(const u16t* __restrict__ Q,
                                              const u16t* __restrict__ K,
                                              const u16t* __restrict__ Vt,
                                              u16t* __restrict__ O) {
  __shared__ u16t smem[40960];  // 80 KB
  u16t* Ps = smem + 32768;

  const int a = blockIdx.x;
  const int bh = blockIdx.y;
  const int b = bh >> 4;
  const int h = bh & 15;
  const size_t rowb = (size_t)b * SEQ;
  const u16t* vtg = Vt + (size_t)h * HDIM * MROWS + (size_t)b * SEQ;

  const int t = threadIdx.x;
  const int lane = t & 63;
  const int w = t >> 6;
  const int l15 = lane & 15;
  const int quad = lane >> 4;
  const int l7 = l15 & 7;
  const float C2 = 0.12751743f;
  const float NEG = -3.0e38f;

  const int krow = t >> 4;
  const int kch = (t & 15) * 8;
  const int vrow = t >> 3;
  const int vch = (t & 7) * 8;
  const int kx = kch ^ ((krow & 7) * 8);
  const int vx = vch ^ ((vrow & 7) * 8);
  const u16t* Kgb = &K[(rowb + krow) * HIDDEN + h * HDIM + kch];
  const u16t* Vgb = vtg + (size_t)vrow * MROWS + vch;

  for (int half = 0; half < 2; ++half) {
    const int qt = half ? (15 - a) : a;
    const int q0 = qt * 128;
    const int nsteps = 2 * (qt + 1);

    uint4 ck0 = *(const uint4*)Kgb;
    uint4 ck1 = *(const uint4*)(Kgb + 32 * HIDDEN);
    uint4 cv0 = *(const uint4*)Vgb;
    uint4 cv1 = *(const uint4*)(Vgb + (size_t)64 * MROWS);

#pragma unroll
    for (int j = 0; j < 4; ++j) {
      int idx = t + j * 512;
      int row = idx >> 4;
      int ch = (idx & 15) * 8;
      *(uint4*)&smem[row * 136 + ch] =
          *(const uint4*)&Q[(rowb + q0 + row) * HIDDEN + h * HDIM + ch];
    }
    __syncthreads();
    v8s qf[4];
#pragma unroll
    for (int ks = 0; ks < 4; ++ks)
      qf[ks] = *(const v8s*)&smem[(w * 16 + l15) * 136 + ks * 32 + quad * 8];
    __syncthreads();

    float mi[4], li[4];
    v4f o[8];
#pragma unroll
    for (int r = 0; r < 4; ++r) { mi[r] = NEG; li[r] = 0.f; }
#pragma unroll
    for (int nt = 0; nt < 8; ++nt) o[nt] = (v4f){0.f, 0.f, 0.f, 0.f};

    for (int kt = 0; kt < nsteps; ++kt) {
      u16t* Kb = smem + (kt & 1) * 16384;
      u16t* Vb = Kb + 8192;
      *(uint4*)&Kb[krow * 128 + kx] = ck0;
      *(uint4*)&Kb[(krow + 32) * 128 + kx] = ck1;
      *(uint4*)&Vb[vrow * 64 + vx] = cv0;
      *(uint4*)&Vb[(vrow + 64) * 64 + vx] = cv1;
      if (kt + 1 < nsteps) {
        const int kv1 = (kt + 1) * 64;
        const u16t* kg = Kgb + (size_t)kv1 * HIDDEN;
        ck0 = *(const uint4*)kg;
        ck1 = *(const uint4*)(kg + 32 * HIDDEN);
        const u16t* vg = Vgb + kv1;
        cv0 = *(const uint4*)vg;
        cv1 = *(const uint4*)(vg + (size_t)64 * MROWS);
      }
      __syncthreads();

      const int kv0 = kt * 64;
      v4f sc[4];
#pragma unroll
      for (int nt = 0; nt < 4; ++nt) {
        sc[nt] = (v4f){0.f, 0.f, 0.f, 0.f};
#pragma unroll
        for (int ks = 0; ks < 4; ++ks) {
          v8s kf = *(const v8s*)&Kb[(nt * 16 + l15) * 128 +
                                    ((ks * 32 + quad * 8) ^ (l7 * 8))];
          sc[nt] = __builtin_amdgcn_mfma_f32_16x16x32_bf16(qf[ks], kf, sc[nt], 0, 0, 0);
        }
      }

      const bool mm = (kv0 + 64 > q0);
#pragma unroll
      for (int r = 0; r < 4; ++r) {
        float sv[4];
#pragma unroll
        for (int nt = 0; nt < 4; ++nt) sv[nt] = sc[nt][r];
        if (mm) {
          int row_g = q0 + w * 16 + quad * 4 + r;
#pragma unroll
          for (int nt = 0; nt < 4; ++nt)
            if (kv0 + nt * 16 + l15 > row_g) sv[nt] = NEG;
        }
        float rm = fmaxf(fmaxf(sv[0], sv[1]), fmaxf(sv[2], sv[3]));
#pragma unroll
        for (int off = 1; off < 16; off <<= 1) rm = fmaxf(rm, __shfl_xor(rm, off));
        float mn = fmaxf(mi[r], rm);
        float alpha = exp2f((mi[r] - mn) * C2);
        float ps = 0.f;
        u16t pb[4];
#pragma unroll
        for (int nt = 0; nt < 4; ++nt) {
          float p = exp2f((sv[nt] - mn) * C2);
          ps += p;
          pb[nt] = f2bf(p);
        }
#pragma unroll
        for (int off = 1; off < 16; off <<= 1) ps += __shfl_xor(ps, off);
        li[r] = li[r] * alpha + ps;
        mi[r] = mn;
#pragma unroll
        for (int nt = 0; nt < 8; ++nt) o[nt][r] *= alpha;
        int rowp = w * 16 + quad * 4 + r;
        int psw = (rowp & 7) * 8;
#pragma unroll
        for (int nt = 0; nt < 4; ++nt)
          Ps[rowp * 64 + ((nt * 16 + l15) ^ psw)] = pb[nt];
      }

#pragma unroll
      for (int ks = 0; ks < 2; ++ks) {
        v8s pf = *(const v8s*)&Ps[(w * 16 + l15) * 64 +
                                  ((ks * 32 + quad * 8) ^ (l7 * 8))];
#pragma unroll
        for (int nt = 0; nt < 8; ++nt) {
          v8s vf = *(const v8s*)&Vb[(nt * 16 + l15) * 64 +
                                    ((ks * 32 + quad * 8) ^ (l7 * 8))];
          o[nt] = __builtin_amdgcn_mfma_f32_16x16x32_bf16(pf, vf, o[nt], 0, 0, 0);
        }
      }
    }

#pragma unroll
    for (int r = 0; r < 4; ++r) {
      float inv = 1.0f / li[r];
      size_t row = rowb + q0 + w * 16 + quad * 4 + r;
#pragma unroll
      for (int nt = 0; nt < 8; ++nt)
        O[row * HIDDEN + h * HDIM + nt * 16 + l15] = f2bf(o[nt][r] * inv);
    }
    __syncthreads();
  }
}

// ---------------------------------------------------------------------------
extern "C" void kernel_launch(void* const* d_in, const int* in_sizes, int n_in,
                              void* d_out, int out_size, void* d_ws, size_t ws_size,
                              hipStream_t stream) {
  const float* X = (const float*)d_in[0];
  const float* Wq = (const float*)d_in[3];
  const float* Wk = (const float*)d_in[4];
  const float* Wv = (const float*)d_in[5];
  const float* Wo = (const float*)d_in[6];
  float* out = (float*)d_out;

  char* wsb = (char*)d_ws;
  const size_t MB = 1024 * 1024;
  u16t* xb = (u16t*)(wsb + 0 * MB);    // 16 MB, dead after QKV gemms
  u16t* q = (u16t*)(wsb + 16 * MB);    // 16 MB
  u16t* k = (u16t*)(wsb + 32 * MB);    // 16 MB
  u16t* vt = (u16t*)(wsb + 48 * MB);   // 16 MB
  u16t* a = xb;                        // flash out aliases xb (xb dead by then)

  dim3 blk(256);
  dim3 fg(8, BATCH * NHEAD);
  const int XN8 = MROWS * HIDDEN / 8;   // 1M
  const int WN8 = HIDDEN * HIDDEN / 8;  // 512K (= 2^19)

  cvt_bf16<<<(XN8 + 255) / 256, blk, 0, stream>>>(X, xb, XN8);

  if (ws_size >= 96 * MB) {
    u16t* wqb = (u16t*)(wsb + 64 * MB);  // wq/wk/wv contiguous: B3 = [6144][2048]
    u16t* wkb = (u16t*)(wsb + 72 * MB);
    u16t* wvb = (u16t*)(wsb + 80 * MB);
    u16t* wob = (u16t*)(wsb + 88 * MB);
    cvt_bf16_w4<<<(4 * WN8) / 256, blk, 0, stream>>>(Wq, Wk, Wv, Wo, wqb, wkb, wvb, wob);

    gemm_fused<0><<<dim3(384), dim3(512), 0, stream>>>(xb, wqb, q, k, vt, nullptr);
    rope_k<<<(MROWS * NHEAD * 64) / 256, blk, 0, stream>>>(q, k);
    flash2<<<fg, dim3(512), 0, stream>>>(q, k, vt, a);
    gemm_fused<1><<<dim3(128), dim3(512), 0, stream>>>(a, wob, nullptr, nullptr, nullptr, out);
  } else {
    dim3 gg(HIDDEN / 128, MROWS / 128);  // (16, 32)
    gemm_a16<0><<<gg, blk, 0, stream>>>(xb, Wq, q);
    gemm_a16<0><<<gg, blk, 0, stream>>>(xb, Wk, k);
    gemm_vt_f32<<<gg, blk, 0, stream>>>(xb, Wv, vt);
    rope_k<<<(MROWS * NHEAD * 64) / 256, blk, 0, stream>>>(q, k);
    flash2<<<fg, dim3(512), 0, stream>>>(q, k, vt, a);
    gemm_a16<1><<<gg, blk, 0, stream>>>(a, Wo, out);
  }
}

// Round 5
// 433.760 us; speedup vs baseline: 1.0151x; 1.0151x over previous
//
#include <hip/hip_runtime.h>
#include <cstdint>

typedef unsigned short u16t;
typedef float v4f __attribute__((ext_vector_type(4)));
typedef short v8s __attribute__((ext_vector_type(8)));

#define HIDDEN 2048
#define NHEAD 16
#define HDIM 128
#define SEQ 2048
#define BATCH 2
#define MROWS (BATCH * SEQ) /* 4096 */

__device__ __forceinline__ float bf2f(u16t u) {
  return __builtin_bit_cast(float, (uint32_t)((uint32_t)u << 16));
}
__device__ __forceinline__ u16t f2bf(float f) {
  uint32_t u = __builtin_bit_cast(uint32_t, f);
  u += 0x7FFFu + ((u >> 16) & 1u);
  return (u16t)(u >> 16);
}
__device__ __forceinline__ ushort4 f2bf4(float4 v) {
  ushort4 r;
  r.x = f2bf(v.x); r.y = f2bf(v.y); r.z = f2bf(v.z); r.w = f2bf(v.w);
  return r;
}

// async global->LDS, 16B per lane. LDS dest must be wave-uniform base + lane*16.
__device__ __forceinline__ void gld_lds16(const u16t* g, u16t* l) {
  __builtin_amdgcn_global_load_lds(
      (const __attribute__((address_space(1))) uint32_t*)g,
      (__attribute__((address_space(3))) uint32_t*)l, 16, 0, 0);
}

// ---------------------------------------------------------------------------
// fp32 -> bf16 elementwise convert (8 elems/thread)
// ---------------------------------------------------------------------------
__global__ __launch_bounds__(256) void cvt_bf16(const float* __restrict__ src,
                                                u16t* __restrict__ dst, int n8) {
  int i = blockIdx.x * 256 + threadIdx.x;
  if (i < n8) {
    float4 a = ((const float4*)src)[2 * i];
    float4 b = ((const float4*)src)[2 * i + 1];
    union { ushort4 h[2]; uint4 u; } pk;
    pk.h[0] = f2bf4(a);
    pk.h[1] = f2bf4(b);
    ((uint4*)dst)[i] = pk.u;
  }
}

// All four weight matrices in one launch (each HIDDEN*HIDDEN, n8 = 2^19 each).
__global__ __launch_bounds__(256) void cvt_bf16_w4(
    const float* __restrict__ s0, const float* __restrict__ s1,
    const float* __restrict__ s2, const float* __restrict__ s3,
    u16t* __restrict__ d0, u16t* __restrict__ d1,
    u16t* __restrict__ d2, u16t* __restrict__ d3) {
  int i = blockIdx.x * 256 + threadIdx.x;
  int sel = i >> 19;          // WN8 == 2^19
  int j = i & 0x7FFFF;
  const float* src = (sel == 0) ? s0 : (sel == 1) ? s1 : (sel == 2) ? s2 : s3;
  u16t* dst = (sel == 0) ? d0 : (sel == 1) ? d1 : (sel == 2) ? d2 : d3;
  float4 a = ((const float4*)src)[2 * j];
  float4 b = ((const float4*)src)[2 * j + 1];
  union { ushort4 h[2]; uint4 u; } pk;
  pk.h[0] = f2bf4(a);
  pk.h[1] = f2bf4(b);
  ((uint4*)dst)[j] = pk.u;
}

// ---------------------------------------------------------------------------
// Pipelined GEMM: C[m,n] = sum_k A[m,k]*B[n,k], bf16 in, fp32 acc. BK=32.
// BM=256, BN = 256 (MODE 0, fused QKV) or 128 (MODE 1, attn-out).
// 512 thr = 8 waves (2M x 4N); per-wave 128 x BN/4.
// 4 LDS buffers, prefetch depth 3, counted vmcnt(2L) at end-of-tile
// (L = loads/tile = 4 or 3; never drained in steady state).
// Rotation safety: tile kt issues writes to buf (kt+3)%4 == (kt-1)%4, whose
// ds_reads completed before tile kt-1's final barrier (lgkmcnt(0) precedes
// its MFMAs); landing is checked by the vmcnt at end of tile kt+2, before
// tile kt+3's reads begin.
// T2 XOR swizzle: pre-swizzled global source -> linear gld_lds dest,
// swizzled ds_read (chunk16 ^= (row>>1)&3). T5 setprio around MFMA.
// XCD-chunked bijective grid swizzle (nwg % 8 == 0).
// MODE 0 epilogue: tx<8 -> q bf16, tx<16 -> k bf16, else vt[n-4096][m] bf16.
// MODE 1 epilogue: f32 C[m][n].
// ---------------------------------------------------------------------------
template <int MODE>
__global__ __launch_bounds__(512) void gemm_pipe(const u16t* __restrict__ A,
                                                 const u16t* __restrict__ B,
                                                 u16t* __restrict__ qo,
                                                 u16t* __restrict__ ko,
                                                 u16t* __restrict__ vto,
                                                 float* __restrict__ fo) {
  constexpr int BN = (MODE == 0) ? 256 : 128;
  constexpr int NX = (MODE == 0) ? 24 : 16;   // grid x tiles
  constexpr int CPX = (MODE == 0) ? 48 : 32;  // WGs per XCD chunk (nwg/8)
  constexpr int NF = BN / 64;                 // per-wave n frags (4 or 2)
  constexpr int BBUF = BN * 32;               // B buffer stride (u16)

  // A: 4 bufs x 16 KB = 32768 u16; B: 4 bufs x BBUF.
  __shared__ u16t lds[32768 + 4 * BBUF];  // MODE0: 128 KB, MODE1: 96 KB
  u16t* Alds = lds;
  u16t* Blds = lds + 32768;

  const int id = blockIdx.x;
  const int swz = (id & 7) * CPX + (id >> 3);
  const int tx = swz % NX;
  const int ty = swz / NX;
  const int n0 = tx * BN;
  const int m0 = ty * 256;

  const int t = threadIdx.x;
  const int lane = t & 63;
  const int w = t >> 6;        // 0..7
  const int wm = w >> 2;       // 0..1  (M half: 128 rows)
  const int wn = w & 3;        // 0..3  (N quarter: BN/4 cols)
  const int l15 = lane & 15;
  const int quad = lane >> 4;

  // staging: thread t covers 16B: row = t>>2 (128-row half), phys chunk t&3.
  // global source fetches logical chunk (t&3) ^ ((t>>3)&3) [inverse swizzle].
  const int srow = t >> 2;
  const int sc8 = ((t & 3) ^ ((t >> 3) & 3)) * 8;
  const u16t* Ag = A + (size_t)(m0 + srow) * HIDDEN + sc8;
  const u16t* Bg = B + (size_t)(n0 + srow) * HIDDEN + sc8;  // MODE1: rows 0..127 only

  // ds_read: logical chunk = quad, physical = quad ^ ((l15>>1)&3).
  const int pcol = (quad ^ ((l15 >> 1) & 3)) * 8;

  v4f acc[8][NF];
#pragma unroll
  for (int i = 0; i < 8; ++i)
#pragma unroll
    for (int j = 0; j < NF; ++j) acc[i][j] = (v4f){0.f, 0.f, 0.f, 0.f};

  const int KT = HIDDEN / 32;  // 64 K-tiles

  // prologue: stage tiles 0,1,2 into bufs 0,1,2 (L loads each, FIFO by tile)
#pragma unroll
  for (int tt = 0; tt < 3; ++tt) {
    const int kb = tt * 32;
    gld_lds16(Ag + kb, &Alds[tt * 8192 + t * 8]);
    gld_lds16(Ag + kb + 128 * HIDDEN, &Alds[tt * 8192 + 4096 + t * 8]);
    gld_lds16(Bg + kb, &Blds[tt * BBUF + t * 8]);
    if (MODE == 0)
      gld_lds16(Bg + kb + 128 * HIDDEN, &Blds[tt * BBUF + 4096 + t * 8]);
  }
  if (MODE == 0)
    asm volatile("s_waitcnt vmcnt(8)" ::: "memory");  // tile 0 landed (2L=8)
  else
    asm volatile("s_waitcnt vmcnt(6)" ::: "memory");  // 2L=6
  __builtin_amdgcn_s_barrier();

  for (int kt = 0; kt < KT; ++kt) {
    const int bu = kt & 3;
    const int b3 = (kt + 3) & 3;
    const int kb3 = kt * 32 + 96;  // K offset of tile kt+3
    const u16t* Asb = &Alds[bu * 8192];
    const u16t* Bsb = &Blds[bu * BBUF];
    const bool pre = (kt + 3 < KT);

    // ---------------- phase 1: m-tiles 0..3 ----------------
    v8s bfr[NF];
#pragma unroll
    for (int j = 0; j < NF; ++j)
      bfr[j] = *(const v8s*)&Bsb[(wn * (BN / 4) + j * 16 + l15) * 32 + pcol];
    v8s af[4];
#pragma unroll
    for (int i = 0; i < 4; ++i)
      af[i] = *(const v8s*)&Asb[(wm * 128 + i * 16 + l15) * 32 + pcol];
    if (pre) {
      gld_lds16(Ag + kb3, &Alds[b3 * 8192 + t * 8]);
      gld_lds16(Bg + kb3, &Blds[b3 * BBUF + t * 8]);
      if (MODE == 1)
        gld_lds16(Ag + kb3 + 128 * HIDDEN, &Alds[b3 * 8192 + 4096 + t * 8]);
    }
    __builtin_amdgcn_s_barrier();
    asm volatile("s_waitcnt lgkmcnt(0)" ::: "memory");
    __builtin_amdgcn_s_setprio(1);
#pragma unroll
    for (int i = 0; i < 4; ++i)
#pragma unroll
      for (int j = 0; j < NF; ++j)
        acc[i][j] = __builtin_amdgcn_mfma_f32_16x16x32_bf16(af[i], bfr[j], acc[i][j], 0, 0, 0);
    __builtin_amdgcn_s_setprio(0);
    __builtin_amdgcn_s_barrier();

    // ---------------- phase 2: m-tiles 4..7 ----------------
#pragma unroll
    for (int i = 0; i < 4; ++i)
      af[i] = *(const v8s*)&Asb[(wm * 128 + 64 + i * 16 + l15) * 32 + pcol];
    if (pre) {
      if (MODE == 0) {
        gld_lds16(Ag + kb3 + 128 * HIDDEN, &Alds[b3 * 8192 + 4096 + t * 8]);
        gld_lds16(Bg + kb3 + 128 * HIDDEN, &Blds[b3 * BBUF + 4096 + t * 8]);
      }
    }
    __builtin_amdgcn_s_barrier();
    asm volatile("s_waitcnt lgkmcnt(0)" ::: "memory");
    __builtin_amdgcn_s_setprio(1);
#pragma unroll
    for (int i = 0; i < 4; ++i)
#pragma unroll
      for (int j = 0; j < NF; ++j)
        acc[4 + i][j] = __builtin_amdgcn_mfma_f32_16x16x32_bf16(af[i], bfr[j], acc[4 + i][j], 0, 0, 0);
    __builtin_amdgcn_s_setprio(0);
    // end-of-tile checkpoint: tile kt+1 must have landed.
    if (kt + 3 < KT) {
      if (MODE == 0)
        asm volatile("s_waitcnt vmcnt(8)" ::: "memory");
      else
        asm volatile("s_waitcnt vmcnt(6)" ::: "memory");
    } else if (kt + 2 < KT) {
      if (MODE == 0)
        asm volatile("s_waitcnt vmcnt(4)" ::: "memory");
      else
        asm volatile("s_waitcnt vmcnt(3)" ::: "memory");
    } else if (kt + 1 < KT) {
      asm volatile("s_waitcnt vmcnt(0)" ::: "memory");
    }
    __builtin_amdgcn_s_barrier();
  }

  // ---------------- epilogue ----------------
  if (MODE == 1) {
#pragma unroll
    for (int i = 0; i < 8; ++i) {
#pragma unroll
      for (int j = 0; j < NF; ++j) {
        int col = n0 + wn * (BN / 4) + j * 16 + l15;
#pragma unroll
        for (int r = 0; r < 4; ++r) {
          int row = m0 + wm * 128 + i * 16 + quad * 4 + r;
          fo[(size_t)row * HIDDEN + col] = acc[i][j][r];
        }
      }
    }
  } else if (tx < 16) {
    // q or k range: bf16 [m][2048]
    u16t* dst = (tx < 8) ? qo : ko;
    const int cb = n0 & 2047;
#pragma unroll
    for (int i = 0; i < 8; ++i) {
#pragma unroll
      for (int j = 0; j < NF; ++j) {
        int col = cb + wn * 64 + j * 16 + l15;
#pragma unroll
        for (int r = 0; r < 4; ++r) {
          int row = m0 + wm * 128 + i * 16 + quad * 4 + r;
          dst[(size_t)row * HIDDEN + col] = f2bf(acc[i][j][r]);
        }
      }
    }
  } else {
    // V range: transposed bf16 vt[n-4096][m], two 128-n half passes via LDS
    const int nv0 = n0 - 4096;
    u16t* Ct = (u16t*)lds;  // [128][264] u16 = 67.5 KB (fits 128 KB)
#pragma unroll
    for (int h = 0; h < 2; ++h) {
      __syncthreads();
      if ((wn >> 1) == h) {
#pragma unroll
        for (int i = 0; i < 8; ++i)
#pragma unroll
          for (int j = 0; j < NF; ++j)
#pragma unroll
            for (int r = 0; r < 4; ++r)
              Ct[((wn & 1) * 64 + j * 16 + l15) * 264 +
                 wm * 128 + i * 16 + quad * 4 + r] = f2bf(acc[i][j][r]);
      }
      __syncthreads();
#pragma unroll
      for (int it = 0; it < 8; ++it) {
        int idx = t + it * 512;   // 0..4095
        int nl = idx >> 5;        // 0..127
        int mc = idx & 31;        // 0..31 (16B chunks over 256 m)
        *(uint4*)&vto[(size_t)(nv0 + h * 128 + nl) * MROWS + m0 + mc * 8] =
            *(const uint4*)&Ct[nl * 264 + mc * 8];
      }
    }
  }
}

// ---------------------------------------------------------------------------
// Fallback GEMM (m97 structure) for small-workspace path: B is fp32.
// ---------------------------------------------------------------------------
template <int OUT_F32>
__global__ __launch_bounds__(256) void gemm_a16(const u16t* __restrict__ A,
                                                const void* __restrict__ Bp,
                                                void* __restrict__ Cp) {
  __shared__ u16t As[128 * 32];
  __shared__ u16t Bs[128 * 32];

  const int n0 = blockIdx.x * 128;
  const int m0 = blockIdx.y * 128;
  const int t = threadIdx.x;
  const int lane = t & 63;
  const int w = t >> 6;
  const int wm = w & 1;
  const int wn = w >> 1;
  const int l15 = lane & 15;
  const int quad = lane >> 4;

  v4f acc[4][4];
#pragma unroll
  for (int i = 0; i < 4; ++i)
#pragma unroll
    for (int j = 0; j < 4; ++j) acc[i][j] = (v4f){0.f, 0.f, 0.f, 0.f};

  for (int kb = 0; kb < HIDDEN; kb += 32) {
#pragma unroll
    for (int j = 0; j < 2; ++j) {
      int idx = t + j * 256;
      int row = idx >> 2;
      int ch = (idx & 3) * 8;
      gld_lds16(&A[(size_t)(m0 + row) * HIDDEN + kb + ch], &As[idx * 8]);
    }
    {
      const float* B = (const float*)Bp;
#pragma unroll
      for (int j = 0; j < 4; ++j) {
        int idx = t + j * 256;
        int row = idx >> 3;
        int c4 = (idx & 7) * 4;
        float4 bv = *(const float4*)&B[(size_t)(n0 + row) * HIDDEN + kb + c4];
        *(ushort4*)&Bs[row * 32 + c4] = f2bf4(bv);
      }
    }
    __syncthreads();

    v8s af[4], bf[4];
#pragma unroll
    for (int mt = 0; mt < 4; ++mt)
      af[mt] = *(const v8s*)&As[(wm * 64 + mt * 16 + l15) * 32 + quad * 8];
#pragma unroll
    for (int nt = 0; nt < 4; ++nt)
      bf[nt] = *(const v8s*)&Bs[(wn * 64 + nt * 16 + l15) * 32 + quad * 8];

#pragma unroll
    for (int mt = 0; mt < 4; ++mt)
#pragma unroll
      for (int nt = 0; nt < 4; ++nt)
        acc[mt][nt] = __builtin_amdgcn_mfma_f32_16x16x32_bf16(af[mt], bf[nt], acc[mt][nt], 0, 0, 0);
    __syncthreads();
  }

#pragma unroll
  for (int mt = 0; mt < 4; ++mt) {
#pragma unroll
    for (int nt = 0; nt < 4; ++nt) {
      int col = n0 + wn * 64 + nt * 16 + l15;
#pragma unroll
      for (int r = 0; r < 4; ++r) {
        int row = m0 + wm * 64 + mt * 16 + quad * 4 + r;
        if (OUT_F32)
          ((float*)Cp)[(size_t)row * HIDDEN + col] = acc[mt][nt][r];
        else
          ((u16t*)Cp)[(size_t)row * HIDDEN + col] = f2bf(acc[mt][nt][r]);
      }
    }
  }
}

// Fallback V-projection with transposed output (fp32 B).
__global__ __launch_bounds__(256) void gemm_vt_f32(const u16t* __restrict__ A,
                                                   const void* __restrict__ Bp,
                                                   u16t* __restrict__ VtOut) {
  __shared__ u16t As[128 * 32];
  __shared__ u16t Bs[128 * 32];
  __shared__ u16t Ct[128 * 136];

  const int n0 = blockIdx.x * 128;
  const int m0 = blockIdx.y * 128;
  const int t = threadIdx.x;
  const int lane = t & 63;
  const int w = t >> 6;
  const int wm = w & 1;
  const int wn = w >> 1;
  const int l15 = lane & 15;
  const int quad = lane >> 4;

  v4f acc[4][4];
#pragma unroll
  for (int i = 0; i < 4; ++i)
#pragma unroll
    for (int j = 0; j < 4; ++j) acc[i][j] = (v4f){0.f, 0.f, 0.f, 0.f};

  for (int kb = 0; kb < HIDDEN; kb += 32) {
#pragma unroll
    for (int j = 0; j < 2; ++j) {
      int idx = t + j * 256;
      int row = idx >> 2;
      int ch = (idx & 3) * 8;
      gld_lds16(&A[(size_t)(m0 + row) * HIDDEN + kb + ch], &As[idx * 8]);
    }
    {
      const float* B = (const float*)Bp;
#pragma unroll
      for (int j = 0; j < 4; ++j) {
        int idx = t + j * 256;
        int row = idx >> 3;
        int c4 = (idx & 7) * 4;
        float4 bv = *(const float4*)&B[(size_t)(n0 + row) * HIDDEN + kb + c4];
        *(ushort4*)&Bs[row * 32 + c4] = f2bf4(bv);
      }
    }
    __syncthreads();

    v8s af[4], bf[4];
#pragma unroll
    for (int mt = 0; mt < 4; ++mt)
      af[mt] = *(const v8s*)&As[(wm * 64 + mt * 16 + l15) * 32 + quad * 8];
#pragma unroll
    for (int nt = 0; nt < 4; ++nt)
      bf[nt] = *(const v8s*)&Bs[(wn * 64 + nt * 16 + l15) * 32 + quad * 8];

#pragma unroll
    for (int mt = 0; mt < 4; ++mt)
#pragma unroll
      for (int nt = 0; nt < 4; ++nt)
        acc[mt][nt] = __builtin_amdgcn_mfma_f32_16x16x32_bf16(af[mt], bf[nt], acc[mt][nt], 0, 0, 0);
    __syncthreads();
  }

#pragma unroll
  for (int mt = 0; mt < 4; ++mt)
#pragma unroll
    for (int nt = 0; nt < 4; ++nt)
#pragma unroll
      for (int r = 0; r < 4; ++r)
        Ct[(wn * 64 + nt * 16 + l15) * 136 + (wm * 64 + mt * 16 + quad * 4 + r)] =
            f2bf(acc[mt][nt][r]);
  __syncthreads();

#pragma unroll
  for (int j = 0; j < 8; ++j) {
    int idx = t + j * 256;
    int nl = idx >> 4;
    int mc = idx & 15;
    *(uint4*)&VtOut[(size_t)(n0 + nl) * MROWS + m0 + mc * 8] =
        *(const uint4*)&Ct[nl * 136 + mc * 8];
  }
}

// ---------------------------------------------------------------------------
// RoPE in-place on q and k (bf16, [m][h*128+d])   (unchanged)
// ---------------------------------------------------------------------------
__global__ __launch_bounds__(256) void rope_k(u16t* __restrict__ q, u16t* __restrict__ k) {
  int idx = blockIdx.x * 256 + threadIdx.x;
  int i = idx & 63;
  int h = (idx >> 6) & (NHEAD - 1);
  int m = idx >> 10;
  int s = m & (SEQ - 1);
  float inv = __expf(-(float)i * 0.14391156831212787f);
  float th = (float)s * inv;
  float sn, cs;
  __sincosf(th, &sn, &cs);
  size_t base = (size_t)m * HIDDEN + h * HDIM + i;
  {
    float a = bf2f(q[base]), b = bf2f(q[base + 64]);
    q[base] = f2bf(a * cs - b * sn);
    q[base + 64] = f2bf(b * cs + a * sn);
  }
  {
    float a = bf2f(k[base]), b = bf2f(k[base + 64]);
    k[base] = f2bf(a * cs - b * sn);
    k[base + 64] = f2bf(b * cs + a * sn);
  }
}

// ---------------------------------------------------------------------------
// Flash attention v4: R1/R3 structure + defer-max (T13, THR=7.84 score units,
// P bounded by 2.0). First tile always rescales (mi starts at -3e38) so the
// initialization path is exact.
// ---------------------------------------------------------------------------
__global__ __launch_bounds__(512) void flash2(const u16t* __restrict__ Q,
                                              const u16t* __restrict__ K,
                                              const u16t* __restrict__ Vt,
                                              u16t* __restrict__ O) {
  __shared__ u16t smem[40960];  // 80 KB
  u16t* Ps = smem + 32768;

  const int a = blockIdx.x;
  const int bh = blockIdx.y;
  const int b = bh >> 4;
  const int h = bh & 15;
  const size_t rowb = (size_t)b * SEQ;
  const u16t* vtg = Vt + (size_t)h * HDIM * MROWS + (size_t)b * SEQ;

  const int t = threadIdx.x;
  const int lane = t & 63;
  const int w = t >> 6;
  const int l15 = lane & 15;
  const int quad = lane >> 4;
  const int l7 = l15 & 7;
  const float C2 = 0.12751743f;
  const float NEG = -3.0e38f;

  const int krow = t >> 4;
  const int kch = (t & 15) * 8;
  const int vrow = t >> 3;
  const int vch = (t & 7) * 8;
  const int kx = kch ^ ((krow & 7) * 8);
  const int vx = vch ^ ((vrow & 7) * 8);
  const u16t* Kgb = &K[(rowb + krow) * HIDDEN + h * HDIM + kch];
  const u16t* Vgb = vtg + (size_t)vrow * MROWS + vch;

  for (int half = 0; half < 2; ++half) {
    const int qt = half ? (15 - a) : a;
    const int q0 = qt * 128;
    const int nsteps = 2 * (qt + 1);

    uint4 ck0 = *(const uint4*)Kgb;
    uint4 ck1 = *(const uint4*)(Kgb + 32 * HIDDEN);
    uint4 cv0 = *(const uint4*)Vgb;
    uint4 cv1 = *(const uint4*)(Vgb + (size_t)64 * MROWS);

#pragma unroll
    for (int j = 0; j < 4; ++j) {
      int idx = t + j * 512;
      int row = idx >> 4;
      int ch = (idx & 15) * 8;
      *(uint4*)&smem[row * 136 + ch] =
          *(const uint4*)&Q[(rowb + q0 + row) * HIDDEN + h * HDIM + ch];
    }
    __syncthreads();
    v8s qf[4];
#pragma unroll
    for (int ks = 0; ks < 4; ++ks)
      qf[ks] = *(const v8s*)&smem[(w * 16 + l15) * 136 + ks * 32 + quad * 8];
    __syncthreads();

    float mi[4], li[4];
    v4f o[8];
#pragma unroll
    for (int r = 0; r < 4; ++r) { mi[r] = NEG; li[r] = 0.f; }
#pragma unroll
    for (int nt = 0; nt < 8; ++nt) o[nt] = (v4f){0.f, 0.f, 0.f, 0.f};

    for (int kt = 0; kt < nsteps; ++kt) {
      u16t* Kb = smem + (kt & 1) * 16384;
      u16t* Vb = Kb + 8192;
      *(uint4*)&Kb[krow * 128 + kx] = ck0;
      *(uint4*)&Kb[(krow + 32) * 128 + kx] = ck1;
      *(uint4*)&Vb[vrow * 64 + vx] = cv0;
      *(uint4*)&Vb[(vrow + 64) * 64 + vx] = cv1;
      if (kt + 1 < nsteps) {
        const int kv1 = (kt + 1) * 64;
        const u16t* kg = Kgb + (size_t)kv1 * HIDDEN;
        ck0 = *(const uint4*)kg;
        ck1 = *(const uint4*)(kg + 32 * HIDDEN);
        const u16t* vg = Vgb + kv1;
        cv0 = *(const uint4*)vg;
        cv1 = *(const uint4*)(vg + (size_t)64 * MROWS);
      }
      __syncthreads();

      const int kv0 = kt * 64;
      v4f sc[4];
#pragma unroll
      for (int nt = 0; nt < 4; ++nt) {
        sc[nt] = (v4f){0.f, 0.f, 0.f, 0.f};
#pragma unroll
        for (int ks = 0; ks < 4; ++ks) {
          v8s kf = *(const v8s*)&Kb[(nt * 16 + l15) * 128 +
                                    ((ks * 32 + quad * 8) ^ (l7 * 8))];
          sc[nt] = __builtin_amdgcn_mfma_f32_16x16x32_bf16(qf[ks], kf, sc[nt], 0, 0, 0);
        }
      }

      const bool mm = (kv0 + 64 > q0);
#pragma unroll
      for (int r = 0; r < 4; ++r) {
        float sv[4];
#pragma unroll
        for (int nt = 0; nt < 4; ++nt) sv[nt] = sc[nt][r];
        if (mm) {
          int row_g = q0 + w * 16 + quad * 4 + r;
#pragma unroll
          for (int nt = 0; nt < 4; ++nt)
            if (kv0 + nt * 16 + l15 > row_g) sv[nt] = NEG;
        }
        float rm = fmaxf(fmaxf(sv[0], sv[1]), fmaxf(sv[2], sv[3]));
#pragma unroll
        for (int off = 1; off < 16; off <<= 1) rm = fmaxf(rm, __shfl_xor(rm, off));
        // defer-max: rescale only when tile max exceeds running max by >7.84
        // (P then bounded by exp2(7.84*C2) ~= 2.0, safe for bf16).
        if (rm > mi[r] + 7.84f) {
          float alpha = exp2f((mi[r] - rm) * C2);
          mi[r] = rm;
          li[r] *= alpha;
#pragma unroll
          for (int nt = 0; nt < 8; ++nt) o[nt][r] *= alpha;
        }
        float ps = 0.f;
        u16t pb[4];
#pragma unroll
        for (int nt = 0; nt < 4; ++nt) {
          float p = exp2f((sv[nt] - mi[r]) * C2);
          ps += p;
          pb[nt] = f2bf(p);
        }
#pragma unroll
        for (int off = 1; off < 16; off <<= 1) ps += __shfl_xor(ps, off);
        li[r] += ps;
        int rowp = w * 16 + quad * 4 + r;
        int psw = (rowp & 7) * 8;
#pragma unroll
        for (int nt = 0; nt < 4; ++nt)
          Ps[rowp * 64 + ((nt * 16 + l15) ^ psw)] = pb[nt];
      }

#pragma unroll
      for (int ks = 0; ks < 2; ++ks) {
        v8s pf = *(const v8s*)&Ps[(w * 16 + l15) * 64 +
                                  ((ks * 32 + quad * 8) ^ (l7 * 8))];
#pragma unroll
        for (int nt = 0; nt < 8; ++nt) {
          v8s vf = *(const v8s*)&Vb[(nt * 16 + l15) * 64 +
                                    ((ks * 32 + quad * 8) ^ (l7 * 8))];
          o[nt] = __builtin_amdgcn_mfma_f32_16x16x32_bf16(pf, vf, o[nt], 0, 0, 0);
        }
      }
    }

#pragma unroll
    for (int r = 0; r < 4; ++r) {
      float inv = 1.0f / li[r];
      size_t row = rowb + q0 + w * 16 + quad * 4 + r;
#pragma unroll
      for (int nt = 0; nt < 8; ++nt)
        O[row * HIDDEN + h * HDIM + nt * 16 + l15] = f2bf(o[nt][r] * inv);
    }
    __syncthreads();
  }
}

// ---------------------------------------------------------------------------
extern "C" void kernel_launch(void* const* d_in, const int* in_sizes, int n_in,
                              void* d_out, int out_size, void* d_ws, size_t ws_size,
                              hipStream_t stream) {
  const float* X = (const float*)d_in[0];
  const float* Wq = (const float*)d_in[3];
  const float* Wk = (const float*)d_in[4];
  const float* Wv = (const float*)d_in[5];
  const float* Wo = (const float*)d_in[6];
  float* out = (float*)d_out;

  char* wsb = (char*)d_ws;
  const size_t MB = 1024 * 1024;
  u16t* xb = (u16t*)(wsb + 0 * MB);    // 16 MB, dead after QKV gemms
  u16t* q = (u16t*)(wsb + 16 * MB);    // 16 MB
  u16t* k = (u16t*)(wsb + 32 * MB);    // 16 MB
  u16t* vt = (u16t*)(wsb + 48 * MB);   // 16 MB
  u16t* a = xb;                        // flash out aliases xb (xb dead by then)

  dim3 blk(256);
  dim3 fg(8, BATCH * NHEAD);
  const int XN8 = MROWS * HIDDEN / 8;   // 1M
  const int WN8 = HIDDEN * HIDDEN / 8;  // 512K (= 2^19)

  cvt_bf16<<<(XN8 + 255) / 256, blk, 0, stream>>>(X, xb, XN8);

  if (ws_size >= 96 * MB) {
    u16t* wqb = (u16t*)(wsb + 64 * MB);  // wq/wk/wv contiguous: B3 = [6144][2048]
    u16t* wkb = (u16t*)(wsb + 72 * MB);
    u16t* wvb = (u16t*)(wsb + 80 * MB);
    u16t* wob = (u16t*)(wsb + 88 * MB);
    cvt_bf16_w4<<<(4 * WN8) / 256, blk, 0, stream>>>(Wq, Wk, Wv, Wo, wqb, wkb, wvb, wob);

    gemm_pipe<0><<<dim3(384), dim3(512), 0, stream>>>(xb, wqb, q, k, vt, nullptr);
    rope_k<<<(MROWS * NHEAD * 64) / 256, blk, 0, stream>>>(q, k);
    flash2<<<fg, dim3(512), 0, stream>>>(q, k, vt, a);
    gemm_pipe<1><<<dim3(256), dim3(512), 0, stream>>>(a, wob, nullptr, nullptr, nullptr, out);
  } else {
    dim3 gg(HIDDEN / 128, MROWS / 128);  // (16, 32)
    gemm_a16<0><<<gg, blk, 0, stream>>>(xb, Wq, q);
    gemm_a16<0><<<gg, blk, 0, stream>>>(xb, Wk, k);
    gemm_vt_f32<<<gg, blk, 0, stream>>>(xb, Wv, vt);
    rope_k<<<(MROWS * NHEAD * 64) / 256, blk, 0, stream>>>(q, k);
    flash2<<<fg, dim3(512), 0, stream>>>(q, k, vt, a);
    gemm_a16<1><<<gg, blk, 0, stream>>>(a, Wo, out);
  }
}